// Round 11
// baseline (210.388 us; speedup 1.0000x reference)
//
#include <hip/hip_runtime.h>
#include <math.h>
#include <stdint.h>

// tgate_hybrid: B=4,S=4096,DIMS=2048,T=10,K=2.
// R11 = R10 bit-identical arithmetic; staging rebuilt on async
// __builtin_amdgcn_global_load_lds (no VGPR round-trip -> kills the
// load serialization diagnosed from R10's ~95% wave stall), wave-private
// LDS double-buffer, explicit vmcnt(4) pipeline, sched_barrier pins.
// Chunk = 16 rows x 64 cols; instr-block pitch 1040 B -> 4-way LDS reads.
// K0 = 16wv+2c+ksl ascending == R10's per-slice order -> same FP path.

#define NROWS   16384
#define DIMS_   2048
#define TT      10

typedef __attribute__((ext_vector_type(8))) short short8;
typedef __attribute__((ext_vector_type(4))) float f32x4;

__device__ __forceinline__ unsigned short bf16_rne(float f) {
    unsigned int u = __float_as_uint(f);
    unsigned int r = u + 0x7fffu + ((u >> 16) & 1u);
    return (unsigned short)(r >> 16);
}

// ---- k0: build B fragments (unchanged since R5; must stay identical).
__global__ __launch_bounds__(256)
void tgate_k0(const float* __restrict__ W_cls,
              const float* __restrict__ W_sparse,
              const float* __restrict__ W_gates,
              unsigned short* __restrict__ frag)
{
    int t = blockIdx.x * 256 + threadIdx.x;
    int K0   = t >> 7;
    int nt   = (t >> 6) & 1;
    int lane = t & 63;
    int n  = nt * 16 + (lane & 15);
    int kb = K0 * 32 + (lane >> 4) * 8;
    short8 hi, lo;
    #pragma unroll
    for (int j = 0; j < 8; ++j) {
        int k = kb + j;
        float w = 0.0f;
        if (n < 10)      w = W_cls[k * TT + n];
        else if (n < 20) w = W_sparse[k * TT + n - 10];
        else if (n < 30) w = W_gates[k * TT + n - 20];
        unsigned short h = bf16_rne(w);
        float back = __uint_as_float(((unsigned int)h) << 16);
        hi[j] = (short)h;
        lo[j] = (short)bf16_rne(w - back);
    }
    short8* fv = reinterpret_cast<short8*>(frag);
    fv[(K0 * 4 + nt * 2 + 0) * 64 + lane] = hi;
    fv[(K0 * 4 + nt * 2 + 1) * 64 + lane] = lo;
}

// issue one chunk: 4 async 1-KB instrs, each 4 rows x 256 B; LDS block pitch 260 floats
__device__ __forceinline__ void issue_chunk(const float* __restrict__ x,
                                            float* bufbase, int row0, int lane,
                                            int colf0)
{
    #pragma unroll
    for (int t = 0; t < 4; ++t) {
        const float* gp = x + (size_t)(row0 + 4 * t + (lane >> 4)) * DIMS_
                            + colf0 + (lane & 15) * 4;
        __builtin_amdgcn_global_load_lds(
            (const __attribute__((address_space(1))) void*)gp,
            (__attribute__((address_space(3))) void*)(bufbase + t * 260),
            16, 0, 0);
    }
}

// compute one chunk (2 k-steps) from an LDS buffer; exact R10 FP path
__device__ __forceinline__ void compute_chunk(const float* Lbuf,
                                              const short8* __restrict__ fv,
                                              int K0b, int lane, int m, int quad,
                                              f32x4& accA, f32x4& accB)
{
    #pragma unroll
    for (int ksl = 0; ksl < 2; ++ksl) {
        const int K0 = K0b + ksl;
        const float* src = Lbuf + (m >> 2) * 260 + (m & 3) * 64 + ksl * 32 + quad * 8;
        float4 b0 = *reinterpret_cast<const float4*>(src);
        float4 b1 = *reinterpret_cast<const float4*>(src + 4);
        float f[8] = {b0.x, b0.y, b0.z, b0.w, b1.x, b1.y, b1.z, b1.w};
        short8 ah, al;
        #pragma unroll
        for (int j = 0; j < 8; ++j) {
            unsigned short hh = bf16_rne(f[j]);               // rne hi (R5..R10 path)
            float back = __uint_as_float(((unsigned int)hh) << 16);
            ah[j] = (short)hh;
            al[j] = (short)bf16_rne(f[j] - back);
        }
        short8 fh0 = fv[(K0 * 4 + 0) * 64 + lane];
        short8 fl0 = fv[(K0 * 4 + 1) * 64 + lane];
        short8 fh1 = fv[(K0 * 4 + 2) * 64 + lane];
        short8 fl1 = fv[(K0 * 4 + 3) * 64 + lane];
        accA = __builtin_amdgcn_mfma_f32_16x16x32_bf16(ah, fh0, accA, 0, 0, 0);
        accA = __builtin_amdgcn_mfma_f32_16x16x32_bf16(al, fh0, accA, 0, 0, 0);
        accA = __builtin_amdgcn_mfma_f32_16x16x32_bf16(ah, fl0, accA, 0, 0, 0);
        accB = __builtin_amdgcn_mfma_f32_16x16x32_bf16(ah, fh1, accB, 0, 0, 0);
        accB = __builtin_amdgcn_mfma_f32_16x16x32_bf16(al, fh1, accB, 0, 0, 0);
        accB = __builtin_amdgcn_mfma_f32_16x16x32_bf16(ah, fl1, accB, 0, 0, 0);
    }
}

// ---- k1: fused full-K MFMA GEMV, async-LDS pipelined + fold + epilogue
__global__ __launch_bounds__(256)
void tgate_k1(const float* __restrict__ x,
              const unsigned short* __restrict__ frag,
              const float* __restrict__ b_cls,
              const float* __restrict__ b_sparse,
              const float* __restrict__ b_gates,
              const float* __restrict__ alpha,
              float* __restrict__ out)
{
    __shared__ alignas(16) float lds[4][2][1040];   // 33280 B; reused for fold

    const int tid   = threadIdx.x;
    const int lane  = tid & 63;
    const int wv    = __builtin_amdgcn_readfirstlane(tid >> 6);
    const int row0  = blockIdx.x * 16;
    const int m     = lane & 15;
    const int quad  = lane >> 4;
    const int cbase = wv * 512;          // wave's contiguous 512-col span

    float* B0 = &lds[wv][0][0];
    float* B1 = &lds[wv][1][0];
    const short8* fv = reinterpret_cast<const short8*>(frag);

    f32x4 acc[2][2];
    #pragma unroll
    for (int h = 0; h < 2; ++h) {
        acc[h][0] = (f32x4){0.f, 0.f, 0.f, 0.f};
        acc[h][1] = (f32x4){0.f, 0.f, 0.f, 0.f};
    }

    // prologue: chunks 0,1 in flight
    __builtin_amdgcn_sched_barrier(0);
    issue_chunk(x, B0, row0, lane, cbase + 0 * 64);
    issue_chunk(x, B1, row0, lane, cbase + 1 * 64);

    // chunks 0..3 -> slice 2wv (acc[0]); issues chunks 2..5
    for (int c = 0; c < 4; ++c) {
        __builtin_amdgcn_s_waitcnt(0x0F74);          // vmcnt(4): this buffer landed
        float* buf = (c & 1) ? B1 : B0;
        compute_chunk(buf, fv, 16 * wv + 2 * c, lane, m, quad, acc[0][0], acc[0][1]);
        __builtin_amdgcn_sched_barrier(0);
        issue_chunk(x, buf, row0, lane, cbase + (c + 2) * 64);
    }
    // chunks 4,5 -> slice 2wv+1 (acc[1]); issues chunks 6,7
    for (int c = 4; c < 6; ++c) {
        __builtin_amdgcn_s_waitcnt(0x0F74);
        float* buf = (c & 1) ? B1 : B0;
        compute_chunk(buf, fv, 16 * wv + 2 * c, lane, m, quad, acc[1][0], acc[1][1]);
        __builtin_amdgcn_sched_barrier(0);
        issue_chunk(x, buf, row0, lane, cbase + (c + 2) * 64);
    }
    // chunk 6 (no more issues)
    __builtin_amdgcn_s_waitcnt(0x0F74);
    compute_chunk(B0, fv, 16 * wv + 12, lane, m, quad, acc[1][0], acc[1][1]);
    // chunk 7: last 4 loads must fully drain
    __builtin_amdgcn_s_waitcnt(0x0F70);              // vmcnt(0)
    compute_chunk(B1, fv, 16 * wv + 14, lane, m, quad, acc[1][0], acc[1][1]);

    // ---- partials to LDS: red[s][row][j], pitch 33 (reuses lds; 4752 floats <= 8320)
    float* red = &lds[0][0][0];
    __syncthreads();
    #pragma unroll
    for (int h = 0; h < 2; ++h) {
        int s = 2 * wv + h;
        #pragma unroll
        for (int r = 0; r < 4; ++r) {
            int row = quad * 4 + r;       // C/D layout (verified m89)
            red[(s * 16 + row) * 33 + m]      = acc[h][0][r];
            red[(s * 16 + row) * 33 + m + 16] = acc[h][1][r];
        }
    }
    __syncthreads();

    // ---- fold: bit-identical to R10 (l=0; s=0..7 ascending)
    float* fold = red + 8 * 16 * 33;
    #pragma unroll
    for (int u = 0; u < 2; ++u) {
        int i = tid * 2 + u;
        int row = i >> 5, j = i & 31;
        float a = 0.0f;
        #pragma unroll
        for (int s = 0; s < 8; ++s) a += red[(s * 16 + row) * 33 + j];
        fold[row * 33 + j] = a;
    }
    __syncthreads();

    // ---- epilogue: lanes 0..15 of wave 0 (R10 verbatim)
    if (tid < 16) {
        const float* l = &fold[tid * 33];
        float lc[TT], lsp[TT], g[TT];
        #pragma unroll
        for (int t = 0; t < TT; ++t) {
            lc[t]  = l[t]      + b_cls[t];
            lsp[t] = l[10 + t] + b_sparse[t];
            float lg = l[20 + t] + b_gates[t];
            g[t] = 1.0f / (1.0f + __expf(-lg));
        }
        float mm = lc[0];
        #pragma unroll
        for (int t = 1; t < TT; ++t) mm = fmaxf(mm, lc[t]);
        float esum = 0.0f, gdot = 0.0f;
        #pragma unroll
        for (int t = 0; t < TT; ++t) {
            float e = __expf(lc[t] - mm);
            esum += e;
            gdot = fmaf(g[t], e, gdot);
        }
        float v1 = lsp[0], v2 = -1e30f, gv1 = g[0], gv2 = 0.0f;
        #pragma unroll
        for (int t = 1; t < TT; ++t) {
            if (lsp[t] > v1)      { v2 = v1; gv2 = gv1; v1 = lsp[t]; gv1 = g[t]; }
            else if (lsp[t] > v2) { v2 = lsp[t]; gv2 = g[t]; }
        }
        float s1 = 1.0f / (1.0f + __expf(v2 - v1));
        float s2 = 1.0f - s1;
        float a  = 1.0f / (1.0f + __expf(-alpha[0]));
        float sparse_dot = fmaf(gv1, s1, gv2 * s2);
        out[row0 + tid] = fmaf(a, sparse_dot, (1.0f - a) * (gdot / esum));
    }
}

extern "C" void kernel_launch(void* const* d_in, const int* in_sizes, int n_in,
                              void* d_out, int out_size, void* d_ws, size_t ws_size,
                              hipStream_t stream) {
    const float* x        = (const float*)d_in[0];
    const float* W_cls    = (const float*)d_in[1];
    const float* b_cls    = (const float*)d_in[2];
    const float* W_sparse = (const float*)d_in[3];
    const float* b_sparse = (const float*)d_in[4];
    const float* W_gates  = (const float*)d_in[5];
    const float* b_gates  = (const float*)d_in[6];
    const float* alpha    = (const float*)d_in[7];
    float* out = (float*)d_out;

    unsigned short* frag = (unsigned short*)d_ws;   // 256 KB

    tgate_k0<<<dim3(32), dim3(256), 0, stream>>>(W_cls, W_sparse, W_gates, frag);
    tgate_k1<<<dim3(NROWS / 16), dim3(256), 0, stream>>>(x, frag, b_cls, b_sparse,
                                                         b_gates, alpha, out);
}

// Round 12
// 204.557 us; speedup vs baseline: 1.0285x; 1.0285x over previous
//
#include <hip/hip_runtime.h>
#include <math.h>
#include <stdint.h>

// tgate_hybrid: B=4,S=4096,DIMS=2048,T=10,K=2.
// R12 = R11 byte-identical EXCEPT aux=2 (NT, non-temporal) on the async
// x-staging loads: x is streamed exactly once; NT skips L2 allocation and
// avoids interaction with the dirty lines left by the harness's 537 MB
// poison + 134 MB restore that immediately precede k1. Cache policy cannot
// alter values -> output must remain exactly absmax 0.00390625.
// (R7/R10/R11: three different load mechanisms converged at the same
// ~2.4 TB/s read plateau -> limiter is downstream of the CU; NT is the
// last numerics-safe lever on the read path.)

#define NROWS   16384
#define DIMS_   2048
#define TT      10

typedef __attribute__((ext_vector_type(8))) short short8;
typedef __attribute__((ext_vector_type(4))) float f32x4;

__device__ __forceinline__ unsigned short bf16_rne(float f) {
    unsigned int u = __float_as_uint(f);
    unsigned int r = u + 0x7fffu + ((u >> 16) & 1u);
    return (unsigned short)(r >> 16);
}

// ---- k0: build B fragments (unchanged since R5; must stay identical).
__global__ __launch_bounds__(256)
void tgate_k0(const float* __restrict__ W_cls,
              const float* __restrict__ W_sparse,
              const float* __restrict__ W_gates,
              unsigned short* __restrict__ frag)
{
    int t = blockIdx.x * 256 + threadIdx.x;
    int K0   = t >> 7;
    int nt   = (t >> 6) & 1;
    int lane = t & 63;
    int n  = nt * 16 + (lane & 15);
    int kb = K0 * 32 + (lane >> 4) * 8;
    short8 hi, lo;
    #pragma unroll
    for (int j = 0; j < 8; ++j) {
        int k = kb + j;
        float w = 0.0f;
        if (n < 10)      w = W_cls[k * TT + n];
        else if (n < 20) w = W_sparse[k * TT + n - 10];
        else if (n < 30) w = W_gates[k * TT + n - 20];
        unsigned short h = bf16_rne(w);
        float back = __uint_as_float(((unsigned int)h) << 16);
        hi[j] = (short)h;
        lo[j] = (short)bf16_rne(w - back);
    }
    short8* fv = reinterpret_cast<short8*>(frag);
    fv[(K0 * 4 + nt * 2 + 0) * 64 + lane] = hi;
    fv[(K0 * 4 + nt * 2 + 1) * 64 + lane] = lo;
}

// issue one chunk: 4 async 1-KB instrs, each 4 rows x 256 B; LDS block pitch 260 floats
// aux=2 -> NT (non-temporal): no L2 allocation for the once-read x stream.
__device__ __forceinline__ void issue_chunk(const float* __restrict__ x,
                                            float* bufbase, int row0, int lane,
                                            int colf0)
{
    #pragma unroll
    for (int t = 0; t < 4; ++t) {
        const float* gp = x + (size_t)(row0 + 4 * t + (lane >> 4)) * DIMS_
                            + colf0 + (lane & 15) * 4;
        __builtin_amdgcn_global_load_lds(
            (const __attribute__((address_space(1))) void*)gp,
            (__attribute__((address_space(3))) void*)(bufbase + t * 260),
            16, 0, 2);
    }
}

// compute one chunk (2 k-steps) from an LDS buffer; exact R10/R11 FP path
__device__ __forceinline__ void compute_chunk(const float* Lbuf,
                                              const short8* __restrict__ fv,
                                              int K0b, int lane, int m, int quad,
                                              f32x4& accA, f32x4& accB)
{
    #pragma unroll
    for (int ksl = 0; ksl < 2; ++ksl) {
        const int K0 = K0b + ksl;
        const float* src = Lbuf + (m >> 2) * 260 + (m & 3) * 64 + ksl * 32 + quad * 8;
        float4 b0 = *reinterpret_cast<const float4*>(src);
        float4 b1 = *reinterpret_cast<const float4*>(src + 4);
        float f[8] = {b0.x, b0.y, b0.z, b0.w, b1.x, b1.y, b1.z, b1.w};
        short8 ah, al;
        #pragma unroll
        for (int j = 0; j < 8; ++j) {
            unsigned short hh = bf16_rne(f[j]);               // rne hi (R5..R11 path)
            float back = __uint_as_float(((unsigned int)hh) << 16);
            ah[j] = (short)hh;
            al[j] = (short)bf16_rne(f[j] - back);
        }
        short8 fh0 = fv[(K0 * 4 + 0) * 64 + lane];
        short8 fl0 = fv[(K0 * 4 + 1) * 64 + lane];
        short8 fh1 = fv[(K0 * 4 + 2) * 64 + lane];
        short8 fl1 = fv[(K0 * 4 + 3) * 64 + lane];
        accA = __builtin_amdgcn_mfma_f32_16x16x32_bf16(ah, fh0, accA, 0, 0, 0);
        accA = __builtin_amdgcn_mfma_f32_16x16x32_bf16(al, fh0, accA, 0, 0, 0);
        accA = __builtin_amdgcn_mfma_f32_16x16x32_bf16(ah, fl0, accA, 0, 0, 0);
        accB = __builtin_amdgcn_mfma_f32_16x16x32_bf16(ah, fh1, accB, 0, 0, 0);
        accB = __builtin_amdgcn_mfma_f32_16x16x32_bf16(al, fh1, accB, 0, 0, 0);
        accB = __builtin_amdgcn_mfma_f32_16x16x32_bf16(ah, fl1, accB, 0, 0, 0);
    }
}

// ---- k1: fused full-K MFMA GEMV, async-LDS pipelined + fold + epilogue
__global__ __launch_bounds__(256)
void tgate_k1(const float* __restrict__ x,
              const unsigned short* __restrict__ frag,
              const float* __restrict__ b_cls,
              const float* __restrict__ b_sparse,
              const float* __restrict__ b_gates,
              const float* __restrict__ alpha,
              float* __restrict__ out)
{
    __shared__ alignas(16) float lds[4][2][1040];   // 33280 B; reused for fold

    const int tid   = threadIdx.x;
    const int lane  = tid & 63;
    const int wv    = __builtin_amdgcn_readfirstlane(tid >> 6);
    const int row0  = blockIdx.x * 16;
    const int m     = lane & 15;
    const int quad  = lane >> 4;
    const int cbase = wv * 512;          // wave's contiguous 512-col span

    float* B0 = &lds[wv][0][0];
    float* B1 = &lds[wv][1][0];
    const short8* fv = reinterpret_cast<const short8*>(frag);

    f32x4 acc[2][2];
    #pragma unroll
    for (int h = 0; h < 2; ++h) {
        acc[h][0] = (f32x4){0.f, 0.f, 0.f, 0.f};
        acc[h][1] = (f32x4){0.f, 0.f, 0.f, 0.f};
    }

    // prologue: chunks 0,1 in flight
    __builtin_amdgcn_sched_barrier(0);
    issue_chunk(x, B0, row0, lane, cbase + 0 * 64);
    issue_chunk(x, B1, row0, lane, cbase + 1 * 64);

    // chunks 0..3 -> slice 2wv (acc[0]); issues chunks 2..5
    for (int c = 0; c < 4; ++c) {
        __builtin_amdgcn_s_waitcnt(0x0F74);          // vmcnt(4): this buffer landed
        float* buf = (c & 1) ? B1 : B0;
        compute_chunk(buf, fv, 16 * wv + 2 * c, lane, m, quad, acc[0][0], acc[0][1]);
        __builtin_amdgcn_sched_barrier(0);
        issue_chunk(x, buf, row0, lane, cbase + (c + 2) * 64);
    }
    // chunks 4,5 -> slice 2wv+1 (acc[1]); issues chunks 6,7
    for (int c = 4; c < 6; ++c) {
        __builtin_amdgcn_s_waitcnt(0x0F74);
        float* buf = (c & 1) ? B1 : B0;
        compute_chunk(buf, fv, 16 * wv + 2 * c, lane, m, quad, acc[1][0], acc[1][1]);
        __builtin_amdgcn_sched_barrier(0);
        issue_chunk(x, buf, row0, lane, cbase + (c + 2) * 64);
    }
    // chunk 6 (no more issues)
    __builtin_amdgcn_s_waitcnt(0x0F74);
    compute_chunk(B0, fv, 16 * wv + 12, lane, m, quad, acc[1][0], acc[1][1]);
    // chunk 7: last 4 loads must fully drain
    __builtin_amdgcn_s_waitcnt(0x0F70);              // vmcnt(0)
    compute_chunk(B1, fv, 16 * wv + 14, lane, m, quad, acc[1][0], acc[1][1]);

    // ---- partials to LDS: red[s][row][j], pitch 33 (reuses lds)
    float* red = &lds[0][0][0];
    __syncthreads();
    #pragma unroll
    for (int h = 0; h < 2; ++h) {
        int s = 2 * wv + h;
        #pragma unroll
        for (int r = 0; r < 4; ++r) {
            int row = quad * 4 + r;       // C/D layout (verified m89)
            red[(s * 16 + row) * 33 + m]      = acc[h][0][r];
            red[(s * 16 + row) * 33 + m + 16] = acc[h][1][r];
        }
    }
    __syncthreads();

    // ---- fold: bit-identical (l=0; s=0..7 ascending)
    float* fold = red + 8 * 16 * 33;
    #pragma unroll
    for (int u = 0; u < 2; ++u) {
        int i = tid * 2 + u;
        int row = i >> 5, j = i & 31;
        float a = 0.0f;
        #pragma unroll
        for (int s = 0; s < 8; ++s) a += red[(s * 16 + row) * 33 + j];
        fold[row * 33 + j] = a;
    }
    __syncthreads();

    // ---- epilogue: lanes 0..15 of wave 0 (verbatim since R5)
    if (tid < 16) {
        const float* l = &fold[tid * 33];
        float lc[TT], lsp[TT], g[TT];
        #pragma unroll
        for (int t = 0; t < TT; ++t) {
            lc[t]  = l[t]      + b_cls[t];
            lsp[t] = l[10 + t] + b_sparse[t];
            float lg = l[20 + t] + b_gates[t];
            g[t] = 1.0f / (1.0f + __expf(-lg));
        }
        float mm = lc[0];
        #pragma unroll
        for (int t = 1; t < TT; ++t) mm = fmaxf(mm, lc[t]);
        float esum = 0.0f, gdot = 0.0f;
        #pragma unroll
        for (int t = 0; t < TT; ++t) {
            float e = __expf(lc[t] - mm);
            esum += e;
            gdot = fmaf(g[t], e, gdot);
        }
        float v1 = lsp[0], v2 = -1e30f, gv1 = g[0], gv2 = 0.0f;
        #pragma unroll
        for (int t = 1; t < TT; ++t) {
            if (lsp[t] > v1)      { v2 = v1; gv2 = gv1; v1 = lsp[t]; gv1 = g[t]; }
            else if (lsp[t] > v2) { v2 = lsp[t]; gv2 = g[t]; }
        }
        float s1 = 1.0f / (1.0f + __expf(v2 - v1));
        float s2 = 1.0f - s1;
        float a  = 1.0f / (1.0f + __expf(-alpha[0]));
        float sparse_dot = fmaf(gv1, s1, gv2 * s2);
        out[row0 + tid] = fmaf(a, sparse_dot, (1.0f - a) * (gdot / esum));
    }
}

extern "C" void kernel_launch(void* const* d_in, const int* in_sizes, int n_in,
                              void* d_out, int out_size, void* d_ws, size_t ws_size,
                              hipStream_t stream) {
    const float* x        = (const float*)d_in[0];
    const float* W_cls    = (const float*)d_in[1];
    const float* b_cls    = (const float*)d_in[2];
    const float* W_sparse = (const float*)d_in[3];
    const float* b_sparse = (const float*)d_in[4];
    const float* W_gates  = (const float*)d_in[5];
    const float* b_gates  = (const float*)d_in[6];
    const float* alpha    = (const float*)d_in[7];
    float* out = (float*)d_out;

    unsigned short* frag = (unsigned short*)d_ws;   // 256 KB

    tgate_k0<<<dim3(32), dim3(256), 0, stream>>>(W_cls, W_sparse, W_gates, frag);
    tgate_k1<<<dim3(NROWS / 16), dim3(256), 0, stream>>>(x, frag, b_cls, b_sparse,
                                                         b_gates, alpha, out);
}